// Round 2
// baseline (1523.417 us; speedup 1.0000x reference)
//
#include <hip/hip_runtime.h>
#include <math.h>

// Problem constants (from reference)
#define BB   16
#define CC   64
#define HH   64
#define WW   64
#define DIN  192   // C*K = 64*3
#define DOUT 128
#define NEXP 8

// tok stride padded to 193: (w*193 + f) % 32 = (w+f)%32 -> max 2-way LDS
// aliasing across 64 lanes, which is free on gfx950.
#define TOKS 193

__global__ __launch_bounds__(256)
void moe_conv2d_fused(const float* __restrict__ x,
                      const float* __restrict__ conv_w,
                      const float* __restrict__ router_w,
                      const float* __restrict__ w_experts,
                      const float* __restrict__ b_experts,
                      const float* __restrict__ w_shared,
                      const float* __restrict__ b_shared,
                      float* __restrict__ out)
{
    __shared__ float tok[64 * TOKS];      // 49408 B
    __shared__ float logits[64 * 8];      // 2048 B
    __shared__ float sg0[64], sg1[64];
    __shared__ int   se0[64], se1[64];

    const int tid = threadIdx.x;
    const int bh  = blockIdx.x;           // 0..1023
    const int b   = bh >> 6;
    const int h   = bh & 63;

    // ---------------- Phase 1: depthwise conv -> tokens ----------------
    // f = 3*c + j uses input channel c and weights conv_w[f,0,:,:]
    for (int i = 0; i < 48; ++i) {
        int idx = i * 256 + tid;          // 0..12287
        int w = idx & 63;                 // lanes sweep w -> coalesced x
        int f = idx >> 6;                 // 0..191
        int c = f / 3;
        const float* wp    = conv_w + f * 9;
        const float* xbase = x + ((size_t)(b * 64 + c) * 64) * 64;
        float acc = 0.f;
        #pragma unroll
        for (int kh = 0; kh < 3; ++kh) {
            int hh = h + kh - 1;
            if (hh < 0 || hh > 63) continue;
            const float* xrow = xbase + hh * 64;
            #pragma unroll
            for (int kw = 0; kw < 3; ++kw) {
                int ww = w + kw - 1;
                if (ww < 0 || ww > 63) continue;
                acc += xrow[ww] * wp[kh * 3 + kw];
            }
        }
        tok[w * TOKS + f] = acc;
    }
    __syncthreads();

    // ---------------- Phase 2: router (fp32, exact-ish to dodge tie flips)
    for (int it = 0; it < 2; ++it) {
        int p = it * 256 + tid;           // 0..511
        int w = p >> 3;
        int e = p & 7;
        const float* tw = tok + w * TOKS;
        const float* rw = router_w + e;   // (DIN, NEXP) row-major
        float acc = 0.f;
        for (int f = 0; f < 192; ++f) acc += tw[f] * rw[f * 8];
        logits[w * 8 + e] = acc;
    }
    __syncthreads();

    if (tid < 64) {
        int w = tid;
        float l[8];
        #pragma unroll
        for (int e = 0; e < 8; ++e) l[e] = logits[w * 8 + e];
        // top-2 of logits == top-2 of softmax probs (monotone).
        // strict > keeps the lowest index on ties, matching lax.top_k.
        int e0 = 0; float l0 = l[0];
        #pragma unroll
        for (int e = 1; e < 8; ++e) if (l[e] > l0) { l0 = l[e]; e0 = e; }
        int e1 = -1; float l1 = -INFINITY;
        #pragma unroll
        for (int e = 0; e < 8; ++e) {
            if (e == e0) continue;
            if (l[e] > l1) { l1 = l[e]; e1 = e; }
        }
        // gates renormalized over the top-2: softmax Z cancels.
        float g0 = 1.f / (1.f + expf(l1 - l0));
        sg0[w] = g0; sg1[w] = 1.f - g0;
        se0[w] = e0; se1[w] = e1;
    }
    __syncthreads();

    // ---------------- Phase 3: gated expert + shared matvec ----------------
    // lane -> token w; 4 output groups of 32 channels each.
    {
        int w  = tid & 63;
        int og = tid >> 6;
        int ob = og * 32;
        float g0 = sg0[w], g1 = sg1[w];
        int   e0 = se0[w], e1 = se1[w];

        float acc[32];
        #pragma unroll
        for (int i = 0; i < 32; ++i)
            acc[i] = b_shared[ob + i]
                   + g0 * b_experts[e0 * 128 + ob + i]
                   + g1 * b_experts[e1 * 128 + ob + i];

        const float* W0 = w_experts + (size_t)e0 * 192 * 128 + ob;
        const float* W1 = w_experts + (size_t)e1 * 192 * 128 + ob;
        const float* Ws = w_shared + ob;
        const float* tw = tok + w * TOKS;

        for (int f = 0; f < 192; ++f) {
            float t  = tw[f];
            float t0 = t * g0;
            float t1 = t * g1;
            const float4* p0 = (const float4*)(W0 + f * 128);
            const float4* p1 = (const float4*)(W1 + f * 128);
            const float4* ps = (const float4*)(Ws + f * 128);
            #pragma unroll
            for (int q = 0; q < 8; ++q) {
                float4 a = p0[q];
                float4 c = p1[q];
                float4 s = ps[q];
                acc[q * 4 + 0] += t0 * a.x + t1 * c.x + t * s.x;
                acc[q * 4 + 1] += t0 * a.y + t1 * c.y + t * s.y;
                acc[q * 4 + 2] += t0 * a.z + t1 * c.z + t * s.z;
                acc[q * 4 + 3] += t0 * a.w + t1 * c.w + t * s.w;
            }
        }

        // out[b, o, h, w] with o = ob..ob+31; lanes sweep w -> coalesced
        float* outp = out + (((size_t)b * 128) * 64 + h) * 64 + w;
        #pragma unroll
        for (int i = 0; i < 32; ++i)
            outp[(size_t)(ob + i) * 4096] = acc[i];
    }
}

extern "C" void kernel_launch(void* const* d_in, const int* in_sizes, int n_in,
                              void* d_out, int out_size, void* d_ws, size_t ws_size,
                              hipStream_t stream)
{
    const float* x         = (const float*)d_in[0];
    const float* conv_w    = (const float*)d_in[1];
    const float* router_w  = (const float*)d_in[2];
    const float* w_experts = (const float*)d_in[3];
    const float* b_experts = (const float*)d_in[4];
    const float* w_shared  = (const float*)d_in[5];
    const float* b_shared  = (const float*)d_in[6];
    float* out = (float*)d_out;

    dim3 grid(BB * HH);   // 1024 blocks, one per (b, h) row of 64 tokens
    dim3 block(256);
    moe_conv2d_fused<<<grid, block, 0, stream>>>(
        x, conv_w, router_w, w_experts, b_experts, w_shared, b_shared, out);
}

// Round 3
// 429.578 us; speedup vs baseline: 3.5463x; 3.5463x over previous
//
#include <hip/hip_runtime.h>
#include <math.h>

// Problem constants
#define BB   16
#define CC   64
#define HH   64
#define WW   64
#define DIN  192     // C*K
#define DOUT 128
#define NEXP 8
#define NMAT 9       // 8 routed experts + 1 shared

// LDS strides chosen for bank spread / 16B alignment
#define TOKSTRIDE 200   // bf16 elems per token row: 400 B (16B-mult, 4t%32 bank spread)
#define OUTSTRIDE 129   // fp32 out accum stride: (129t+o)%32=(t+o)%32 conflict-free
#define LOGSTRIDE 9     // logits stride: odd -> 2-way max on atomic adds
#define MAXROWS 320     // worst case padded bucket rows (<=288)
#define MAXTILES 20     // worst case M-tiles (<=18)

typedef short bf16x8 __attribute__((ext_vector_type(8)));
typedef float f32x4  __attribute__((ext_vector_type(4)));

__device__ __forceinline__ unsigned short f2bf(float f) {
    union { float f; unsigned u; } v; v.f = f;
    unsigned u = v.u;
    u += 0x7fffu + ((u >> 16) & 1u);   // RNE (inputs finite)
    return (unsigned short)(u >> 16);
}

// ---------------- prep: fp32 weights -> bf16, transposed to [e][n][k] ----------
__global__ __launch_bounds__(256)
void prep_weights(const float* __restrict__ w_experts,
                  const float* __restrict__ w_shared,
                  unsigned short* __restrict__ wt)
{
    int e = blockIdx.x;                        // 0..8
    const float* src = (e < 8) ? (w_experts + (size_t)e * DIN * DOUT) : w_shared;
    unsigned short* dst = wt + (size_t)e * DOUT * DIN;
    for (int idx = threadIdx.x; idx < DOUT * DIN; idx += 256) {
        int n = idx / DIN, k = idx - n * DIN;  // dst[n][k] = src[k][n]
        dst[idx] = f2bf(src[k * DOUT + n]);
    }
}

// ---------------- main fused kernel: one block per (b,h) row of 64 tokens ------
__global__ __launch_bounds__(256)
void moe_conv2d_mfma(const float* __restrict__ x,
                     const float* __restrict__ conv_w,
                     const float* __restrict__ router_w,
                     const unsigned short* __restrict__ wt,   // [9][128][192] bf16
                     const float* __restrict__ b_experts,
                     const float* __restrict__ b_shared,
                     float* __restrict__ out)
{
    __shared__ __attribute__((aligned(16))) unsigned short tokbf[64 * TOKSTRIDE]; // 25.6 KB
    __shared__ float out_lds[64 * OUTSTRIDE];                                     // 33.0 KB
    __shared__ float rw[DIN * NEXP];                                              // 6.0 KB
    __shared__ float logits[64 * LOGSTRIDE];                                      // 2.3 KB
    __shared__ float sg0[64], sg1[64];
    __shared__ int   se0[64], se1[64];
    __shared__ int   rowtok[MAXROWS];
    __shared__ float rowgate[MAXROWS];
    __shared__ int   cbuf[NMAT];
    __shared__ int   tilexp[MAXTILES], tilebase[MAXTILES];
    __shared__ int   ntiles_s;

    const int tid = threadIdx.x;
    const int bh  = blockIdx.x;
    const int b   = bh >> 6;
    const int h   = bh & 63;

    // ---- init: router weights to LDS, zero logits ----
    for (int idx = tid; idx < DIN * NEXP; idx += 256) rw[idx] = router_w[idx];
    for (int idx = tid; idx < 64 * LOGSTRIDE; idx += 256) logits[idx] = 0.f;
    __syncthreads();

    // ---- phase 1: depthwise conv -> bf16 tokens; fused fp32 router partials ----
    // thread handles fixed token w = tid&63; f = i*4 + (tid>>6)  (wave-uniform f)
    {
        const int w  = tid & 63;
        const int fq = tid >> 6;
        float lacc[8];
        #pragma unroll
        for (int e = 0; e < 8; ++e) lacc[e] = 0.f;

        for (int i = 0; i < 48; ++i) {
            int f = i * 4 + fq;               // 0..191
            int c = f / 3;
            const float* wp    = conv_w + f * 9;
            const float* xbase = x + ((size_t)(b * 64 + c) * 64) * 64;
            float acc = 0.f;
            #pragma unroll
            for (int kh = 0; kh < 3; ++kh) {
                int hh = h + kh - 1;
                if (hh < 0 || hh > 63) continue;
                const float* xrow = xbase + hh * 64;
                #pragma unroll
                for (int kw = 0; kw < 3; ++kw) {
                    int ww = w + kw - 1;
                    if (ww < 0 || ww > 63) continue;
                    acc += xrow[ww] * wp[kh * 3 + kw];
                }
            }
            tokbf[w * TOKSTRIDE + f] = f2bf(acc);
            const float* rwf = rw + f * 8;    // wave-uniform addr -> LDS broadcast
            #pragma unroll
            for (int e = 0; e < 8; ++e) lacc[e] += acc * rwf[e];
        }
        #pragma unroll
        for (int e = 0; e < 8; ++e)
            atomicAdd(&logits[w * LOGSTRIDE + e], lacc[e]);  // 4 threads/(w,e)
    }
    __syncthreads();

    // ---- phase 2a: top-2 per token (fp32 logits; strict > == lax.top_k ties) ----
    if (tid < 64) {
        int w = tid;
        float l[8];
        #pragma unroll
        for (int e = 0; e < 8; ++e) l[e] = logits[w * LOGSTRIDE + e];
        int e0 = 0; float l0 = l[0];
        #pragma unroll
        for (int e = 1; e < 8; ++e) if (l[e] > l0) { l0 = l[e]; e0 = e; }
        int e1 = -1; float l1 = -INFINITY;
        #pragma unroll
        for (int e = 0; e < 8; ++e) {
            if (e == e0) continue;
            if (l[e] > l1) { l1 = l[e]; e1 = e; }
        }
        float g0 = 1.f / (1.f + expf(l1 - l0));   // softmax Z cancels in renorm
        sg0[w] = g0; sg1[w] = 1.f - g0;
        se0[w] = e0; se1[w] = e1;
    }
    __syncthreads();

    // ---- phase 2b: bias init of out accumulator + bucket counts ----
    for (int idx = tid; idx < 64 * DOUT; idx += 256) {
        int t = idx >> 7, o = idx & 127;
        out_lds[t * OUTSTRIDE + o] = b_shared[o]
            + sg0[t] * b_experts[se0[t] * DOUT + o]
            + sg1[t] * b_experts[se1[t] * DOUT + o];
    }
    if (tid < 8) {
        int c = 0;
        for (int t = 0; t < 64; ++t) c += (se0[t] == tid) + (se1[t] == tid);
        cbuf[tid] = c;
    } else if (tid == 8) cbuf[8] = 64;           // shared expert: every token
    __syncthreads();

    // ---- phase 2c: row table (padded to 16-row M-tiles) ----
    if (tid < NMAT) {
        int e = tid;
        int start = 0, tb = 0;
        for (int e2 = 0; e2 < e; ++e2) {
            int ce = cbuf[e2];
            int tl = (ce + 15) >> 4;
            start += tl << 4; tb += tl;
        }
        int ce = cbuf[e];
        int tl = (ce + 15) >> 4;
        for (int j = 0; j < tl; ++j) { tilexp[tb + j] = e; tilebase[tb + j] = start + (j << 4); }
        if (e == 8) ntiles_s = tb + tl;
        int j = 0;
        if (e < 8) {
            for (int t = 0; t < 64; ++t) {
                if (se0[t] == e) { rowtok[start + j] = t; rowgate[start + j] = sg0[t]; ++j; }
                if (se1[t] == e) { rowtok[start + j] = t; rowgate[start + j] = sg1[t]; ++j; }
            }
        } else {
            for (int t = 0; t < 64; ++t) { rowtok[start + j] = t; rowgate[start + j] = 1.f; ++j; }
        }
        for (; j < (tl << 4); ++j) { rowtok[start + j] = 0; rowgate[start + j] = 0.f; }
    }
    __syncthreads();

    // ---- phase 3: bucketed MFMA GEMM, gated LDS scatter ----
    {
        const int wave = tid >> 6;
        const int lane = tid & 63;
        const int m16  = lane & 15;
        const int quad = lane >> 4;
        const int nt   = ntiles_s;

        for (int ti = wave; ti < nt; ti += 4) {
            int e    = tilexp[ti];
            int base = tilebase[ti];
            // A fragments: A[m=lane&15][k=quad*8+j], 6 k-steps of 32
            int tA = rowtok[base + m16];
            bf16x8 a[6];
            #pragma unroll
            for (int ks = 0; ks < 6; ++ks)
                a[ks] = *(const bf16x8*)(tokbf + tA * TOKSTRIDE + ks * 32 + quad * 8);
            // scatter map for C rows: row = quad*4 + reg
            int st[4]; float sgt[4];
            #pragma unroll
            for (int i2 = 0; i2 < 4; ++i2) {
                int r = base + quad * 4 + i2;
                st[i2] = rowtok[r]; sgt[i2] = rowgate[r];
            }
            const unsigned short* we = wt + (size_t)e * DOUT * DIN;
            for (int n = 0; n < 8; ++n) {
                // B[k=quad*8+j][n=lane&15] from Wt[e][n][k] (contiguous k)
                const unsigned short* wp = we + (size_t)(n * 16 + m16) * DIN + quad * 8;
                f32x4 acc = {0.f, 0.f, 0.f, 0.f};
                #pragma unroll
                for (int ks = 0; ks < 6; ++ks) {
                    bf16x8 bfr = *(const bf16x8*)(wp + ks * 32);
                    acc = __builtin_amdgcn_mfma_f32_16x16x32_bf16(a[ks], bfr, acc, 0, 0, 0);
                }
                int ncol = n * 16 + m16;     // C/D: col=lane&15, row=quad*4+reg
                #pragma unroll
                for (int i2 = 0; i2 < 4; ++i2)
                    atomicAdd(&out_lds[st[i2] * OUTSTRIDE + ncol], sgt[i2] * acc[i2]);
            }
        }
    }
    __syncthreads();

    // ---- phase 4: write out[b, o, h, w], lanes sweep w -> coalesced ----
    {
        float* outp = out + (((size_t)b * DOUT) * 64 + h) * 64;
        for (int idx = tid; idx < 64 * DOUT; idx += 256) {
            int w = idx & 63, o = idx >> 6;
            outp[(size_t)o * 4096 + w] = out_lds[w * OUTSTRIDE + o];
        }
    }
}

extern "C" void kernel_launch(void* const* d_in, const int* in_sizes, int n_in,
                              void* d_out, int out_size, void* d_ws, size_t ws_size,
                              hipStream_t stream)
{
    const float* x         = (const float*)d_in[0];
    const float* conv_w    = (const float*)d_in[1];
    const float* router_w  = (const float*)d_in[2];
    const float* w_experts = (const float*)d_in[3];
    const float* b_experts = (const float*)d_in[4];
    const float* w_shared  = (const float*)d_in[5];
    const float* b_shared  = (const float*)d_in[6];
    float* out = (float*)d_out;
    unsigned short* wt = (unsigned short*)d_ws;   // 9*128*192*2 = 442368 B

    prep_weights<<<dim3(NMAT), dim3(256), 0, stream>>>(w_experts, w_shared, wt);
    moe_conv2d_mfma<<<dim3(BB * HH), dim3(256), 0, stream>>>(
        x, conv_w, router_w, wt, b_experts, b_shared, out);
}